// Round 1
// baseline (177.847 us; speedup 1.0000x reference)
//
#include <hip/hip_runtime.h>
#include <stdint.h>

#define NROWS 16384
#define SPLITN 100
#define IDIM 128
#define NH 4
#define PD 64
#define ROWLEN (SPLITN * IDIM)   // 12800
#define ODIM (NH * PD)           // 256

typedef float f32x4 __attribute__((ext_vector_type(4)));
typedef short s16x8 __attribute__((ext_vector_type(8)));
typedef unsigned short u16x8 __attribute__((ext_vector_type(8)));

__device__ __forceinline__ unsigned short f32_to_bf16(float f) {
  uint32_t u = __float_as_uint(f);
  u += 0x7FFFu + ((u >> 16) & 1u);   // RNE
  return (unsigned short)(u >> 16);
}

#if __has_builtin(__builtin_amdgcn_exp2f)
__device__ __forceinline__ float fexp2(float x) { return __builtin_amdgcn_exp2f(x); }
#else
__device__ __forceinline__ float fexp2(float x) { return exp2f(x); }
#endif

template <int IMM>
__device__ __forceinline__ float swz_f(float v) {
  return __int_as_float(__builtin_amdgcn_ds_swizzle(__float_as_int(v), IMM));
}

// ---------- prep: wq[h][i] = sum_o W[h][i][o] * q[h][o] ----------
__global__ void prep_wq(const float* __restrict__ W, const float* __restrict__ q,
                        float* __restrict__ wq) {
  int item = blockIdx.x * 256 + threadIdx.x;
  if (item >= NH * IDIM) return;
  int h = item >> 7, i = item & (IDIM - 1);
  const float* wrow = W + (size_t)(h * IDIM + i) * PD;
  const float* qh = q + h * PD;
  float s = 0.f;
#pragma unroll 8
  for (int o = 0; o < PD; ++o) s = __builtin_fmaf(wrow[o], qh[o], s);
  wq[item] = s;
}

// ---------- prep: W -> bf16 MFMA B-fragment-packed ----------
// frag f = ((h*4+kb)*4+of); lane l elem j holds W[h][kb*32+(l>>4)*8+j][of*16+(l&15)]
__global__ void prep_wp(const float* __restrict__ W, unsigned short* __restrict__ Wp) {
  int flat = blockIdx.x * 256 + threadIdx.x;  // 64 frags * 512 = 32768
  if (flat >= 64 * 512) return;
  int f = flat >> 9;
  int rem = flat & 511;
  int l = rem >> 3, j = rem & 7;
  int of = f & 3, kb = (f >> 2) & 3, h = f >> 4;
  int k = kb * 32 + (l >> 4) * 8 + j;
  int o = of * 16 + (l & 15);
  Wp[flat] = f32_to_bf16(W[(size_t)(h * IDIM + k) * PD + o]);
}

// ---------- k1: fused score + online softmax + weighted pooling ----------
// one wave per row; 4 independent 16-lane streams over s; lane owns 8 i's.
__global__ __launch_bounds__(256) void k1(const float* __restrict__ x,
                                          const float* __restrict__ wq,
                                          unsigned short* __restrict__ ybf) {
  const int lane = threadIdx.x & 63;
  const int g = lane >> 4;        // s-stream
  const int li = lane & 15;       // i-octet index
  const int row = (blockIdx.x << 2) | (threadIdx.x >> 6);
  const float* xrow = x + (size_t)row * ROWLEN;

  float wqr[NH][8];
#pragma unroll
  for (int h = 0; h < NH; ++h) {
    f32x4 a = *(const f32x4*)(wq + h * IDIM + li * 8);
    f32x4 b = *(const f32x4*)(wq + h * IDIM + li * 8 + 4);
#pragma unroll
    for (int j = 0; j < 4; ++j) { wqr[h][j] = a[j]; wqr[h][4 + j] = b[j]; }
  }

  float y[NH][8];
  float m[NH], lsum[NH], mL[NH];
#pragma unroll
  for (int h = 0; h < NH; ++h) {
    m[h] = -INFINITY; mL[h] = -INFINITY; lsum[h] = 0.f;
#pragma unroll
    for (int j = 0; j < 8; ++j) y[h][j] = 0.f;
  }
  const float L2E = 1.44269504088896340736f;

  const float* pc = xrow + g * IDIM + li * 8;
  f32x4 xa = *(const f32x4*)pc;
  f32x4 xb = *(const f32x4*)(pc + 4);

  for (int it = 0; it < 25; ++it) {
    f32x4 na = {}, nb = {};
    const float* pn = pc + 4 * IDIM;
    if (it < 24) { na = *(const f32x4*)pn; nb = *(const f32x4*)(pn + 4); }

    float xv[8];
#pragma unroll
    for (int j = 0; j < 4; ++j) { xv[j] = xa[j]; xv[4 + j] = xb[j]; }

    float part[NH];
#pragma unroll
    for (int h = 0; h < NH; ++h) {
      float p = xv[0] * wqr[h][0];
#pragma unroll
      for (int j = 1; j < 8; ++j) p = __builtin_fmaf(xv[j], wqr[h][j], p);
      part[h] = p;
    }
    // reduce over the 16 lanes of this group (xor 1,2,4,8)
#pragma unroll
    for (int h = 0; h < NH; ++h) {
      part[h] += swz_f<0x041F>(part[h]);
      part[h] += swz_f<0x081F>(part[h]);
      part[h] += swz_f<0x101F>(part[h]);
      part[h] += swz_f<0x201F>(part[h]);
    }
#pragma unroll
    for (int h = 0; h < NH; ++h) {
      float sc = part[h];
      sc = sc > 0.f ? sc : 0.2f * sc;      // leaky_relu
      if (sc > m[h] + 8.0f) {              // defer-max rescale (rare)
        float scale = fexp2(mL[h] - sc * L2E);  // exp2(-inf)=0 on first hit
        lsum[h] *= scale;
#pragma unroll
        for (int j = 0; j < 8; ++j) y[h][j] *= scale;
        m[h] = sc; mL[h] = sc * L2E;
      }
      float w = fexp2(__builtin_fmaf(sc, L2E, -mL[h]));
      lsum[h] += w;
#pragma unroll
      for (int j = 0; j < 8; ++j) y[h][j] = __builtin_fmaf(w, xv[j], y[h][j]);
    }
    xa = na; xb = nb; pc = pn;
  }

  // flash-merge the 4 streams (xor 16 then 32)
#pragma unroll
  for (int st = 16; st <= 32; st <<= 1) {
#pragma unroll
    for (int h = 0; h < NH; ++h) {
      float mo = __shfl_xor(m[h], st, 64);
      float lo = __shfl_xor(lsum[h], st, 64);
      float mn = fmaxf(m[h], mo);
      float ea = fexp2((m[h] - mn) * L2E);
      float eb = fexp2((mo - mn) * L2E);
      lsum[h] = lsum[h] * ea + lo * eb;
#pragma unroll
      for (int j = 0; j < 8; ++j) {
        float yo = __shfl_xor(y[h][j], st, 64);
        y[h][j] = y[h][j] * ea + yo * eb;
      }
      m[h] = mn;
    }
  }

  // group g stores head g (all lanes hold the full merged state)
  float lg = lsum[0];
  float ys[8];
#pragma unroll
  for (int j = 0; j < 8; ++j) ys[j] = y[0][j];
#pragma unroll
  for (int h = 1; h < NH; ++h) {
    bool sel = (g == h);
    lg = sel ? lsum[h] : lg;
#pragma unroll
    for (int j = 0; j < 8; ++j) ys[j] = sel ? y[h][j] : ys[j];
  }
  float inv = 1.0f / lg;
  u16x8 pk;
#pragma unroll
  for (int j = 0; j < 8; ++j) pk[j] = f32_to_bf16(ys[j] * inv);
  *(u16x8*)(ybf + (size_t)row * 512 + g * 128 + li * 8) = pk;
}

// ---------- k2: pooled = y_bf16 @ W_bf16 (per head), overwrite d_out fp32 ----------
// NOTE: ybf and out alias the same buffer (d_out). No __restrict__ here; every
// store depends on the loads, and each wave's load/store byte ranges coincide.
__global__ __launch_bounds__(256) void k2(const unsigned short* ybf,
                                          const unsigned short* __restrict__ Wp,
                                          float* out) {
  const int h = threadIdx.x >> 6;   // wave -> head
  const int l = threadIdx.x & 63;
  const int rowb = blockIdx.x * 32;

  s16x8 Bf[4][4];
#pragma unroll
  for (int kb = 0; kb < 4; ++kb)
#pragma unroll
    for (int of = 0; of < 4; ++of)
      Bf[kb][of] = *(const s16x8*)(Wp + (size_t)(((h * 4 + kb) * 4 + of) * 512 + l * 8));

  s16x8 Af[2][4];
#pragma unroll
  for (int mf = 0; mf < 2; ++mf)
#pragma unroll
    for (int kb = 0; kb < 4; ++kb) {
      int r = rowb + mf * 16 + (l & 15);
      Af[mf][kb] = *(const s16x8*)(ybf + (size_t)r * 512 + h * 128 + kb * 32 + (l >> 4) * 8);
    }

  f32x4 acc[2][4];
#pragma unroll
  for (int mf = 0; mf < 2; ++mf)
#pragma unroll
    for (int of = 0; of < 4; ++of) acc[mf][of] = (f32x4){0.f, 0.f, 0.f, 0.f};

#pragma unroll
  for (int kb = 0; kb < 4; ++kb)
#pragma unroll
    for (int mf = 0; mf < 2; ++mf)
#pragma unroll
      for (int of = 0; of < 4; ++of)
        acc[mf][of] = __builtin_amdgcn_mfma_f32_16x16x32_bf16(Af[mf][kb], Bf[kb][of],
                                                              acc[mf][of], 0, 0, 0);

#pragma unroll
  for (int mf = 0; mf < 2; ++mf)
#pragma unroll
    for (int of = 0; of < 4; ++of)
#pragma unroll
      for (int reg = 0; reg < 4; ++reg) {
        int r = rowb + mf * 16 + (l >> 4) * 4 + reg;
        int o = of * 16 + (l & 15);
        out[(size_t)r * ODIM + h * PD + o] = acc[mf][of][reg];
      }
}

extern "C" void kernel_launch(void* const* d_in, const int* in_sizes, int n_in,
                              void* d_out, int out_size, void* d_ws, size_t ws_size,
                              hipStream_t stream) {
  const float* x = (const float*)d_in[0];
  const float* W = (const float*)d_in[1];
  const float* q = (const float*)d_in[2];
  float* out = (float*)d_out;
  float* wq = (float*)d_ws;                                     // 2 KB
  unsigned short* Wp = (unsigned short*)((char*)d_ws + 2048);   // 64 KB
  unsigned short* ybf = (unsigned short*)d_out;                 // y staged in d_out

  prep_wq<<<2, 256, 0, stream>>>(W, q, wq);
  prep_wp<<<128, 256, 0, stream>>>(W, Wp);
  k1<<<NROWS / 4, 256, 0, stream>>>(x, wq, ybf);
  k2<<<NROWS / 32, 256, 0, stream>>>(ybf, Wp, out);
}